// Round 8
// baseline (70.720 us; speedup 1.0000x reference)
//
#include <hip/hip_runtime.h>

// DiscreteHazardLoss — two-kernel, fence-free.
// R4 lesson: per-block __threadfence + device atomicAdd = L2 writeback storm (+90us).
// R7: double-buffered register pipeline => 54.0us (main ~5.9 TB/s of 6.29 ceiling).
// R8: BYTE reduction. Only columns j<=t are needed; a row's 2nd 64B cacheline
// (cols 16..31) is fetched iff t>=16 (P=1/2, t~U[0,32)). Conditional per-lane
// v-loads skip it => ~67MB (23%) less HBM traffic. ev load narrowed to the one
// lane per row that needs it (L2-request saving, HBM-neutral).
//
// loss_i = -( sum_{j<t} log(1-sigmoid(x_ij)+eps) + (ev ? log(sigmoid(x_it)+eps)
//                                                     : log(1-sigmoid(x_it)+eps)) )
// Identities (eps=1e-7 negligible for |x|<~5.8):
//   log(1-sigmoid(x)) = -softplus(x);  log(sigmoid(x)) = x - softplus(x)
// => per element j<=t: -softplus(x_j); plus +x_t iff (j==t && ev). out=-(sum)/B.

constexpr int T_BINS        = 32;
constexpr int BLOCK         = 256;
constexpr int LANES_PER_ROW = 8;                      // 8 lanes x float4 = 32 cols
constexpr int ROWS_PER_ITER = BLOCK / LANES_PER_ROW;  // 32 rows/iter/block
constexpr int NBLOCKS       = 2048;
constexpr int U             = 4;                      // rows-groups per batch
constexpr int STEP          = U * ROWS_PER_ITER;      // 128 rows per batch
constexpr int PIPE          = 2 * STEP;               // 256 rows per pipelined iter

__device__ __forceinline__ int detect_shift(const int* tb, int lane) {
    // int64 LE with values in [0,32) => all odd int32 words are 0.
    // P(false positive on real int32 data) = (1/32)^64 ~ 1e-96.
    const int probe = tb[2 * lane + 1];
    return (__ballot(probe != 0) == 0ULL) ? 1 : 0;
}

__device__ __forceinline__ void block_reduce_store(float acc, float* dst, int tid) {
    #pragma unroll
    for (int off = 32; off > 0; off >>= 1)
        acc += __shfl_down(acc, off, 64);
    __shared__ float sw[BLOCK / 64];
    if ((tid & 63) == 0) sw[tid >> 6] = acc;
    __syncthreads();
    if (tid == 0) *dst = sw[0] + sw[1] + sw[2] + sw[3];
}

// Fast path: rows_per_block % PIPE == 0, grid covers B exactly, 32-bit indexing.
__global__ __launch_bounds__(BLOCK) void dhl_main_fast(
    const float4* __restrict__ logits4,
    const int*    __restrict__ tb,
    const int*    __restrict__ ev,
    float*        __restrict__ partials,
    int rows_per_block)
{
    const int tid   = threadIdx.x;
    const int shift = detect_shift(tb, tid & 63);
    const int lane8 = tid & (LANES_PER_ROW - 1);
    const int rloc  = tid >> 3;
    const int j0    = lane8 * 4;
    const int rbase = blockIdx.x * rows_per_block;

    float4 vA[U]; int tA[U]; int eA[U];
    float4 vB[U]; int tB[U]; int eB[U];
    float acc = 0.0f;

    // t first (clamped), then t-conditioned masked loads of v (and the single
    // needed lane's e). Lanes with j0 > t skip their float4 => the row's 2nd
    // 64B line is never fetched when t < 16.
#define DHL_LOAD(V, T, E, base)                                                 \
    _Pragma("unroll")                                                           \
    for (int u = 0; u < U; ++u) {                                               \
        const int row_ = (base) + u * ROWS_PER_ITER + rloc;                     \
        T[u] = min(max(tb[row_ << shift], 0), T_BINS - 1);                      \
    }                                                                           \
    _Pragma("unroll")                                                           \
    for (int u = 0; u < U; ++u) {                                               \
        const int row_ = (base) + u * ROWS_PER_ITER + rloc;                     \
        E[u] = ((T[u] >> 2) == lane8) ? ev[row_] : 0;                           \
        V[u] = (j0 <= T[u]) ? logits4[row_ * LANES_PER_ROW + lane8]             \
                            : make_float4(0.0f, 0.0f, 0.0f, 0.0f);              \
    }

#define DHL_COMPUTE(V, T, E)                                                    \
    _Pragma("unroll")                                                           \
    for (int u = 0; u < U; ++u) {                                               \
        const int tt_ = T[u];                                                   \
        const float xs_[4] = {V[u].x, V[u].y, V[u].z, V[u].w};                  \
        _Pragma("unroll")                                                       \
        for (int c = 0; c < 4; ++c) {                                           \
            const float x_ = xs_[c];                                            \
            const float L_ = __logf(1.0f + __expf(x_));                         \
            const int j_ = j0 + c;                                              \
            if (j_ <= tt_) acc -= L_;                                           \
            if (j_ == tt_ && E[u] == 1) acc += x_;                              \
        }                                                                       \
    }

    DHL_LOAD(vA, tA, eA, rbase)
    for (int i = 0; i < rows_per_block; i += PIPE) {
        DHL_LOAD(vB, tB, eB, rbase + i + STEP)
        DHL_COMPUTE(vA, tA, eA)
        if (i + PIPE < rows_per_block) {
            DHL_LOAD(vA, tA, eA, rbase + i + PIPE)
        }
        DHL_COMPUTE(vB, tB, eB)
    }
#undef DHL_LOAD
#undef DHL_COMPUTE

    block_reduce_store(acc, &partials[blockIdx.x], tid);
}

// Safe path: arbitrary B (64-bit rows, bounds guard).
__global__ __launch_bounds__(BLOCK) void dhl_main_safe(
    const float4* __restrict__ logits4,
    const int*    __restrict__ tb,
    const int*    __restrict__ ev,
    float*        __restrict__ partials,
    long long nrows, int rows_per_block)
{
    const int tid   = threadIdx.x;
    const int shift = detect_shift(tb, tid & 63);
    const int lane8 = tid & (LANES_PER_ROW - 1);
    const int rloc  = tid >> 3;
    const int j0    = lane8 * 4;
    const long long rbase = (long long)blockIdx.x * rows_per_block;

    float acc = 0.0f;
    for (int i = 0; i < rows_per_block; i += ROWS_PER_ITER) {
        const long long row = rbase + i + rloc;
        if (row < nrows) {
            const float4 v = logits4[row * LANES_PER_ROW + lane8];
            int t = tb[row << shift];
            t = min(max(t, 0), T_BINS - 1);
            const int e = ev[row];
            const float xs[4] = {v.x, v.y, v.z, v.w};
            #pragma unroll
            for (int c = 0; c < 4; ++c) {
                const float x = xs[c];
                const float L = __logf(1.0f + __expf(x));
                const int j = j0 + c;
                if (j <= t) acc -= L;
                if (j == t && e == 1) acc += x;
            }
        }
    }
    block_reduce_store(acc, &partials[blockIdx.x], tid);
}

__global__ __launch_bounds__(BLOCK) void dhl_finalize(
    const float* __restrict__ partials, int n, float* __restrict__ out, float scale)
{
    const int tid = threadIdx.x;
    float acc = 0.0f;
    for (int i = tid; i < n; i += BLOCK) acc += partials[i];
    #pragma unroll
    for (int off = 32; off > 0; off >>= 1)
        acc += __shfl_down(acc, off, 64);
    __shared__ float sw[BLOCK / 64];
    if ((tid & 63) == 0) sw[tid >> 6] = acc;
    __syncthreads();
    if (tid == 0)
        out[0] = (sw[0] + sw[1] + sw[2] + sw[3]) * scale;   // scale = -1/B
}

extern "C" void kernel_launch(void* const* d_in, const int* in_sizes, int n_in,
                              void* d_out, int out_size, void* d_ws, size_t ws_size,
                              hipStream_t stream) {
    const float4* logits4 = (const float4*)d_in[0];
    const int*    tb      = (const int*)d_in[1];
    const int*    ev      = (const int*)d_in[2];
    float*        out     = (float*)d_out;
    const int B = in_sizes[1];   // rows

    float* partials = (float*)d_ws;

    int rows_per_block = (B + NBLOCKS - 1) / NBLOCKS;
    rows_per_block = ((rows_per_block + PIPE - 1) / PIPE) * PIPE;
    const int nblocks = (B + rows_per_block - 1) / rows_per_block;

    const bool fast = (B % rows_per_block == 0) && (B <= (1 << 27));
    if (fast) {
        dhl_main_fast<<<nblocks, BLOCK, 0, stream>>>(logits4, tb, ev, partials, rows_per_block);
    } else {
        dhl_main_safe<<<nblocks, BLOCK, 0, stream>>>(logits4, tb, ev, partials,
                                                     (long long)B, rows_per_block);
    }
    dhl_finalize<<<1, BLOCK, 0, stream>>>(partials, nblocks, out, -1.0f / (float)B);
}

// Round 9
// 55.681 us; speedup vs baseline: 1.2701x; 1.2701x over previous
//
#include <hip/hip_runtime.h>

// DiscreteHazardLoss — two-kernel, fence-free.
// R4: no cross-block fences (L2 writeback storm, +90us).
// R7: A/B register pipeline => 54.0us (main ~5.9 TB/s).
// R8 FAILED (+16us): masked v-load created t->v dependency INSIDE the load
//   batch => ~600cyc serialized stall per batch.
// R9: byte-skip kept, dependency fixed:
//   (a) address-clamp instead of branch: lanes with j0>t read line 1 of the
//       SAME row (already fetched) => row's 2nd 64B line fetched iff t>=16
//       (P=1/2) => ~67MB (23%) less traffic, no divergence.
//   (b) t prefetched 3 batches ahead (4-slot rotating buffer, literal indices
//       via hand-unrolled x4 loop) => t ready long before v-address calc.
//
// loss_i = -( sum_{j<t} log(1-sigmoid(x_ij)+eps) + (ev ? log(sigmoid(x_it)+eps)
//                                                     : log(1-sigmoid(x_it)+eps)) )
// log(1-sigmoid(x)) = -softplus(x);  log(sigmoid(x)) = x - softplus(x)
// => per element j<=t: -softplus(x_j); plus +x_t iff (j==t && ev). out=-(sum)/B.

constexpr int T_BINS        = 32;
constexpr int BLOCK         = 256;
constexpr int LANES_PER_ROW = 8;                      // 8 lanes x float4 = 32 cols
constexpr int ROWS_PER_ITER = BLOCK / LANES_PER_ROW;  // 32 rows/iter/block
constexpr int NBLOCKS       = 2048;
constexpr int U             = 4;                      // row-groups per batch
constexpr int STEP          = U * ROWS_PER_ITER;      // 128 rows per batch
constexpr int CHUNK         = 4 * STEP;               // 512 rows per unrolled iter

__device__ __forceinline__ int detect_shift(const int* tb, int lane) {
    // int64 LE with values in [0,32) => all odd int32 words are 0.
    // P(false positive on real int32 data) = (1/32)^64 ~ 1e-96.
    const int probe = tb[2 * lane + 1];
    return (__ballot(probe != 0) == 0ULL) ? 1 : 0;
}

__device__ __forceinline__ void block_reduce_store(float acc, float* dst, int tid) {
    #pragma unroll
    for (int off = 32; off > 0; off >>= 1)
        acc += __shfl_down(acc, off, 64);
    __shared__ float sw[BLOCK / 64];
    if ((tid & 63) == 0) sw[tid >> 6] = acc;
    __syncthreads();
    if (tid == 0) *dst = sw[0] + sw[1] + sw[2] + sw[3];
}

// Fast path: rows_per_block % CHUNK == 0, grid covers B exactly, 32-bit indexing.
__global__ __launch_bounds__(BLOCK) void dhl_main_fast(
    const float4* __restrict__ logits4,
    const int*    __restrict__ tb,
    const int*    __restrict__ ev,
    float*        __restrict__ partials,
    int rows_per_block)
{
    const int tid   = threadIdx.x;
    const int shift = detect_shift(tb, tid & 63);
    const int lane8 = tid & (LANES_PER_ROW - 1);
    const int rloc  = tid >> 3;
    const int j0    = lane8 * 4;
    const int rbase = blockIdx.x * rows_per_block;
    const int nb    = rows_per_block / STEP;          // batches; multiple of 4, >=4

    int    tq[4][U];    // t, 4 batches in flight (literal indices only)
    float4 vq[2][U];    // logits, 2 batches in flight
    int    eq[2][U];    // events, 2 batches in flight
    float  acc = 0.0f;

    // t pre-clamped to [0,31] (needed for both predicates and address safety)
#define DHL_LOADT(Td, b)                                                        \
    _Pragma("unroll")                                                           \
    for (int u = 0; u < U; ++u) {                                               \
        const int row_ = rbase + (b) * STEP + u * ROWS_PER_ITER + rloc;         \
        Td[u] = min(max(tb[row_ << shift], 0), T_BINS - 1);                     \
    }

    // Address-clamped v-load: lanes with j0 > t read line 1 of the same row
    // (cols 0..15) => no divergence, and the 2nd 64B line is only fetched
    // when t >= 16. Garbage lanes are dead via the j<=t predicates.
#define DHL_LOADVE(Vd, Ed, Ts, b)                                               \
    _Pragma("unroll")                                                           \
    for (int u = 0; u < U; ++u) {                                               \
        const int row_ = rbase + (b) * STEP + u * ROWS_PER_ITER + rloc;         \
        const int col_ = (j0 <= Ts[u]) ? lane8 : (lane8 & 3);                   \
        Vd[u] = logits4[row_ * LANES_PER_ROW + col_];                           \
        Ed[u] = ev[row_];                                                       \
    }

#define DHL_COMPUTE(Vs, Ts, Es)                                                 \
    _Pragma("unroll")                                                           \
    for (int u = 0; u < U; ++u) {                                               \
        const int tt_ = Ts[u];                                                  \
        const float xs_[4] = {Vs[u].x, Vs[u].y, Vs[u].z, Vs[u].w};              \
        _Pragma("unroll")                                                       \
        for (int c = 0; c < 4; ++c) {                                           \
            const float x_ = xs_[c];                                            \
            const float L_ = __logf(1.0f + __expf(x_));                         \
            const int j_ = j0 + c;                                              \
            if (j_ <= tt_) acc -= L_;                                           \
            if (j_ == tt_ && Es[u] == 1) acc += x_;                             \
        }                                                                       \
    }

    // Steady state for step k: t[k&3] holds batch k (issued at step k-3);
    // v[k&1]/e[k&1] hold batch k (issued at step k-1, mask from t issued k-3).
#define DHL_STEP(jj)                                                            \
    DHL_LOADT(tq[((jj) + 3) & 3], min(b4 + (jj) + 3, nb - 1))                   \
    DHL_LOADVE(vq[((jj) + 1) & 1], eq[((jj) + 1) & 1], tq[((jj) + 1) & 3],      \
               min(b4 + (jj) + 1, nb - 1))                                      \
    DHL_COMPUTE(vq[(jj) & 1], tq[(jj) & 3], eq[(jj) & 1])

    // Prologue: t for batches 0..2; v/e for batch 0 (one-time stall on t0).
    DHL_LOADT(tq[0], 0)
    DHL_LOADT(tq[1], 1)
    DHL_LOADT(tq[2], 2)
    DHL_LOADVE(vq[0], eq[0], tq[0], 0)

    for (int b4 = 0; b4 < nb; b4 += 4) {
        DHL_STEP(0)
        DHL_STEP(1)
        DHL_STEP(2)
        DHL_STEP(3)
    }
#undef DHL_STEP
#undef DHL_COMPUTE
#undef DHL_LOADVE
#undef DHL_LOADT

    block_reduce_store(acc, &partials[blockIdx.x], tid);
}

// Safe path: arbitrary B (64-bit rows, bounds guard) — R7 structure.
__global__ __launch_bounds__(BLOCK) void dhl_main_safe(
    const float4* __restrict__ logits4,
    const int*    __restrict__ tb,
    const int*    __restrict__ ev,
    float*        __restrict__ partials,
    long long nrows, int rows_per_block)
{
    const int tid   = threadIdx.x;
    const int shift = detect_shift(tb, tid & 63);
    const int lane8 = tid & (LANES_PER_ROW - 1);
    const int rloc  = tid >> 3;
    const int j0    = lane8 * 4;
    const long long rbase = (long long)blockIdx.x * rows_per_block;

    float acc = 0.0f;
    for (int i = 0; i < rows_per_block; i += ROWS_PER_ITER) {
        const long long row = rbase + i + rloc;
        if (row < nrows) {
            const float4 v = logits4[row * LANES_PER_ROW + lane8];
            int t = tb[row << shift];
            t = min(max(t, 0), T_BINS - 1);
            const int e = ev[row];
            const float xs[4] = {v.x, v.y, v.z, v.w};
            #pragma unroll
            for (int c = 0; c < 4; ++c) {
                const float x = xs[c];
                const float L = __logf(1.0f + __expf(x));
                const int j = j0 + c;
                if (j <= t) acc -= L;
                if (j == t && e == 1) acc += x;
            }
        }
    }
    block_reduce_store(acc, &partials[blockIdx.x], tid);
}

__global__ __launch_bounds__(BLOCK) void dhl_finalize(
    const float* __restrict__ partials, int n, float* __restrict__ out, float scale)
{
    const int tid = threadIdx.x;
    float acc = 0.0f;
    for (int i = tid; i < n; i += BLOCK) acc += partials[i];
    #pragma unroll
    for (int off = 32; off > 0; off >>= 1)
        acc += __shfl_down(acc, off, 64);
    __shared__ float sw[BLOCK / 64];
    if ((tid & 63) == 0) sw[tid >> 6] = acc;
    __syncthreads();
    if (tid == 0)
        out[0] = (sw[0] + sw[1] + sw[2] + sw[3]) * scale;   // scale = -1/B
}

extern "C" void kernel_launch(void* const* d_in, const int* in_sizes, int n_in,
                              void* d_out, int out_size, void* d_ws, size_t ws_size,
                              hipStream_t stream) {
    const float4* logits4 = (const float4*)d_in[0];
    const int*    tb      = (const int*)d_in[1];
    const int*    ev      = (const int*)d_in[2];
    float*        out     = (float*)d_out;
    const int B = in_sizes[1];   // rows

    float* partials = (float*)d_ws;

    int rows_per_block = (B + NBLOCKS - 1) / NBLOCKS;
    rows_per_block = ((rows_per_block + CHUNK - 1) / CHUNK) * CHUNK;
    const int nblocks = (B + rows_per_block - 1) / rows_per_block;

    const bool fast = (B % rows_per_block == 0) && (B <= (1 << 27));
    if (fast) {
        dhl_main_fast<<<nblocks, BLOCK, 0, stream>>>(logits4, tb, ev, partials, rows_per_block);
    } else {
        dhl_main_safe<<<nblocks, BLOCK, 0, stream>>>(logits4, tb, ev, partials,
                                                     (long long)B, rows_per_block);
    }
    dhl_finalize<<<1, BLOCK, 0, stream>>>(partials, nblocks, out, -1.0f / (float)B);
}

// Round 10
// 53.837 us; speedup vs baseline: 1.3136x; 1.0342x over previous
//
#include <hip/hip_runtime.h>

// DiscreteHazardLoss — two-kernel, fence-free. FINAL (= R7, the proven best).
// Session ledger:
//  R1  3-dispatch, scalar structure ................ 59.9us
//  R3/R4 fused last-block-done (+fence+atomic) ..... 148-150us (L2 writeback storm)
//  R5  2-dispatch, fence-free ...................... 57.8us
//  R6  unroll-4 batched loads ...................... 56.3us
//  R7  A/B double-buffered register pipeline ....... 54.0us  <= this kernel
//  R8  t-masked loads (t->v dep in batch) .......... 70.7us FAILED
//  R9  addr-clamp byte-skip + deep t-prefetch ...... 55.7us FAILED: no byte
//      savings — HBM/L2 fetch granule is the 128B line = one full row, so
//      skipping cols 16..31 never skips a line. Logits traffic irreducible.
// Floor: 293.6MB / 6.29TB/s = 46.7us main + ~2us finalize + ~2us gap ~ 51us.
// R7 is within ~6% of that => roofline.
//
// loss_i = -( sum_{j<t} log(1-sigmoid(x_ij)+eps) + (ev ? log(sigmoid(x_it)+eps)
//                                                     : log(1-sigmoid(x_it)+eps)) )
// Identities (eps=1e-7 negligible for |x|<~5.8):
//   log(1-sigmoid(x)) = -softplus(x);  log(sigmoid(x)) = x - softplus(x)
// => per element j<=t: -softplus(x_j); plus +x_t iff (j==t && ev). out=-(sum)/B.

constexpr int T_BINS        = 32;
constexpr int BLOCK         = 256;
constexpr int LANES_PER_ROW = 8;                      // 8 lanes x float4 = 32 cols
constexpr int ROWS_PER_ITER = BLOCK / LANES_PER_ROW;  // 32 rows/iter/block
constexpr int NBLOCKS       = 2048;
constexpr int U             = 4;                      // rows-groups per batch
constexpr int STEP          = U * ROWS_PER_ITER;      // 128 rows per batch
constexpr int PIPE          = 2 * STEP;               // 256 rows per pipelined iter

__device__ __forceinline__ int detect_shift(const int* tb, int lane) {
    // int64 LE with values in [0,32) => all odd int32 words are 0.
    // P(false positive on real int32 data) = (1/32)^64 ~ 1e-96.
    const int probe = tb[2 * lane + 1];
    return (__ballot(probe != 0) == 0ULL) ? 1 : 0;
}

__device__ __forceinline__ void block_reduce_store(float acc, float* dst, int tid) {
    #pragma unroll
    for (int off = 32; off > 0; off >>= 1)
        acc += __shfl_down(acc, off, 64);
    __shared__ float sw[BLOCK / 64];
    if ((tid & 63) == 0) sw[tid >> 6] = acc;
    __syncthreads();
    if (tid == 0) *dst = sw[0] + sw[1] + sw[2] + sw[3];
}

// Fast path: rows_per_block % PIPE == 0, grid covers B exactly, 32-bit indexing.
__global__ __launch_bounds__(BLOCK) void dhl_main_fast(
    const float4* __restrict__ logits4,
    const int*    __restrict__ tb,
    const int*    __restrict__ ev,
    float*        __restrict__ partials,
    int rows_per_block)
{
    const int tid   = threadIdx.x;
    const int shift = detect_shift(tb, tid & 63);
    const int lane8 = tid & (LANES_PER_ROW - 1);
    const int rloc  = tid >> 3;
    const int j0    = lane8 * 4;
    const int rbase = blockIdx.x * rows_per_block;

    float4 vA[U]; int tA[U]; int eA[U];
    float4 vB[U]; int tB[U]; int eB[U];
    float acc = 0.0f;

#define DHL_LOAD(V, T, E, base)                                                 \
    _Pragma("unroll")                                                           \
    for (int u = 0; u < U; ++u) {                                               \
        const int row_ = (base) + u * ROWS_PER_ITER + rloc;                     \
        V[u] = logits4[row_ * LANES_PER_ROW + lane8];                           \
        T[u] = tb[row_ << shift];                                               \
        E[u] = ev[row_];                                                        \
    }

#define DHL_COMPUTE(V, T, E)                                                    \
    _Pragma("unroll")                                                           \
    for (int u = 0; u < U; ++u) {                                               \
        const int tt_ = min(max(T[u], 0), T_BINS - 1);                          \
        const float xs_[4] = {V[u].x, V[u].y, V[u].z, V[u].w};                  \
        _Pragma("unroll")                                                       \
        for (int c = 0; c < 4; ++c) {                                           \
            const float x_ = xs_[c];                                            \
            const float L_ = __logf(1.0f + __expf(x_));                         \
            const int j_ = j0 + c;                                              \
            if (j_ <= tt_) acc -= L_;                                           \
            if (j_ == tt_ && E[u] == 1) acc += x_;                              \
        }                                                                       \
    }

    DHL_LOAD(vA, tA, eA, rbase)
    for (int i = 0; i < rows_per_block; i += PIPE) {
        DHL_LOAD(vB, tB, eB, rbase + i + STEP)
        DHL_COMPUTE(vA, tA, eA)
        if (i + PIPE < rows_per_block) {
            DHL_LOAD(vA, tA, eA, rbase + i + PIPE)
        }
        DHL_COMPUTE(vB, tB, eB)
    }
#undef DHL_LOAD
#undef DHL_COMPUTE

    block_reduce_store(acc, &partials[blockIdx.x], tid);
}

// Safe path: arbitrary B (64-bit rows, bounds guard).
__global__ __launch_bounds__(BLOCK) void dhl_main_safe(
    const float4* __restrict__ logits4,
    const int*    __restrict__ tb,
    const int*    __restrict__ ev,
    float*        __restrict__ partials,
    long long nrows, int rows_per_block)
{
    const int tid   = threadIdx.x;
    const int shift = detect_shift(tb, tid & 63);
    const int lane8 = tid & (LANES_PER_ROW - 1);
    const int rloc  = tid >> 3;
    const int j0    = lane8 * 4;
    const long long rbase = (long long)blockIdx.x * rows_per_block;

    float acc = 0.0f;
    for (int i = 0; i < rows_per_block; i += ROWS_PER_ITER) {
        const long long row = rbase + i + rloc;
        if (row < nrows) {
            const float4 v = logits4[row * LANES_PER_ROW + lane8];
            int t = tb[row << shift];
            t = min(max(t, 0), T_BINS - 1);
            const int e = ev[row];
            const float xs[4] = {v.x, v.y, v.z, v.w};
            #pragma unroll
            for (int c = 0; c < 4; ++c) {
                const float x = xs[c];
                const float L = __logf(1.0f + __expf(x));
                const int j = j0 + c;
                if (j <= t) acc -= L;
                if (j == t && e == 1) acc += x;
            }
        }
    }
    block_reduce_store(acc, &partials[blockIdx.x], tid);
}

__global__ __launch_bounds__(BLOCK) void dhl_finalize(
    const float* __restrict__ partials, int n, float* __restrict__ out, float scale)
{
    const int tid = threadIdx.x;
    float acc = 0.0f;
    for (int i = tid; i < n; i += BLOCK) acc += partials[i];
    #pragma unroll
    for (int off = 32; off > 0; off >>= 1)
        acc += __shfl_down(acc, off, 64);
    __shared__ float sw[BLOCK / 64];
    if ((tid & 63) == 0) sw[tid >> 6] = acc;
    __syncthreads();
    if (tid == 0)
        out[0] = (sw[0] + sw[1] + sw[2] + sw[3]) * scale;   // scale = -1/B
}

extern "C" void kernel_launch(void* const* d_in, const int* in_sizes, int n_in,
                              void* d_out, int out_size, void* d_ws, size_t ws_size,
                              hipStream_t stream) {
    const float4* logits4 = (const float4*)d_in[0];
    const int*    tb      = (const int*)d_in[1];
    const int*    ev      = (const int*)d_in[2];
    float*        out     = (float*)d_out;
    const int B = in_sizes[1];   // rows

    float* partials = (float*)d_ws;

    int rows_per_block = (B + NBLOCKS - 1) / NBLOCKS;
    rows_per_block = ((rows_per_block + PIPE - 1) / PIPE) * PIPE;
    const int nblocks = (B + rows_per_block - 1) / rows_per_block;

    const bool fast = (B % rows_per_block == 0) && (B <= (1 << 27));
    if (fast) {
        dhl_main_fast<<<nblocks, BLOCK, 0, stream>>>(logits4, tb, ev, partials, rows_per_block);
    } else {
        dhl_main_safe<<<nblocks, BLOCK, 0, stream>>>(logits4, tb, ev, partials,
                                                     (long long)B, rows_per_block);
    }
    dhl_finalize<<<1, BLOCK, 0, stream>>>(partials, nblocks, out, -1.0f / (float)B);
}